// Round 1
// baseline (1766.531 us; speedup 1.0000x reference)
//
#include <hip/hip_runtime.h>
#include <hip/hip_bf16.h>
#include <type_traits>

// Problem dims
#define NB 128
#define NT 256
#define NS 256
#define NH 512
#define NE 256
#define NV 10000

using bf16 = __hip_bfloat16;

__device__ __forceinline__ float bfu2f(unsigned short u) {
    return __uint_as_float(((unsigned int)u) << 16);
}
__device__ __forceinline__ float sigmf(float x) { return 1.f / (1.f + expf(-x)); }

// ---------------------------------------------------------------------------
// Generic tiled GEMM:  C[M,N] (+)= A[M,K] @ Bw[N,K]^T
// A: float or bf16 (row-major, leading dim lda)
// Bw: float (row-major, leading dim ldb) -- weight matrices, X @ W.T form
// CT: float or bf16; BETA: 0 = overwrite, 1 = accumulate (CT must be float)
// 128x128 tile, BK=16, 256 threads, 8x8 per thread (2x2 sub-blocks of 4).
// ---------------------------------------------------------------------------
template <typename AT, typename CT, int BETA>
__global__ __launch_bounds__(256) void gemm_nt(const AT* __restrict__ A, int lda,
                                               const float* __restrict__ Bw, int ldb,
                                               CT* __restrict__ C, int ldc,
                                               int M, int N, int K) {
    __shared__ float As[16][132];
    __shared__ float Bs[16][132];
    const int tid = threadIdx.x;
    const int tx = tid & 15;
    const int ty = tid >> 4;
    const int m0 = blockIdx.y * 128;
    const int n0 = blockIdx.x * 128;
    const int lr = tid >> 2;         // 0..63
    const int lk = (tid & 3) << 2;   // 0,4,8,12

    float acc[8][8];
#pragma unroll
    for (int i = 0; i < 8; ++i)
#pragma unroll
        for (int j = 0; j < 8; ++j) acc[i][j] = 0.f;

    for (int k0 = 0; k0 < K; k0 += 16) {
#pragma unroll
        for (int half = 0; half < 2; ++half) {
            const int r = lr + half * 64;
            float av0 = 0.f, av1 = 0.f, av2 = 0.f, av3 = 0.f;
            const int gm = m0 + r;
            if (gm < M) {
                if constexpr (std::is_same<AT, float>::value) {
                    const float4 v = *reinterpret_cast<const float4*>(A + (size_t)gm * lda + k0 + lk);
                    av0 = v.x; av1 = v.y; av2 = v.z; av3 = v.w;
                } else {
                    const ushort4 v = *reinterpret_cast<const ushort4*>(
                        reinterpret_cast<const unsigned short*>(A) + (size_t)gm * lda + k0 + lk);
                    av0 = bfu2f(v.x); av1 = bfu2f(v.y); av2 = bfu2f(v.z); av3 = bfu2f(v.w);
                }
            }
            As[lk + 0][r] = av0; As[lk + 1][r] = av1; As[lk + 2][r] = av2; As[lk + 3][r] = av3;

            float bv0 = 0.f, bv1 = 0.f, bv2 = 0.f, bv3 = 0.f;
            const int gn = n0 + r;
            if (gn < N) {
                const float4 v = *reinterpret_cast<const float4*>(Bw + (size_t)gn * ldb + k0 + lk);
                bv0 = v.x; bv1 = v.y; bv2 = v.z; bv3 = v.w;
            }
            Bs[lk + 0][r] = bv0; Bs[lk + 1][r] = bv1; Bs[lk + 2][r] = bv2; Bs[lk + 3][r] = bv3;
        }
        __syncthreads();
#pragma unroll
        for (int kk = 0; kk < 16; ++kk) {
            float a[8], b[8];
            *reinterpret_cast<float4*>(&a[0]) = *reinterpret_cast<const float4*>(&As[kk][ty * 4]);
            *reinterpret_cast<float4*>(&a[4]) = *reinterpret_cast<const float4*>(&As[kk][64 + ty * 4]);
            *reinterpret_cast<float4*>(&b[0]) = *reinterpret_cast<const float4*>(&Bs[kk][tx * 4]);
            *reinterpret_cast<float4*>(&b[4]) = *reinterpret_cast<const float4*>(&Bs[kk][64 + tx * 4]);
#pragma unroll
            for (int i = 0; i < 8; ++i)
#pragma unroll
                for (int j = 0; j < 8; ++j) acc[i][j] = fmaf(a[i], b[j], acc[i][j]);
        }
        __syncthreads();
    }

#pragma unroll
    for (int i = 0; i < 8; ++i) {
        const int gm = m0 + ((i < 4) ? (ty * 4 + i) : (64 + ty * 4 + i - 4));
        if (gm >= M) continue;
#pragma unroll
        for (int j = 0; j < 8; ++j) {
            const int gn = n0 + ((j < 4) ? (tx * 4 + j) : (64 + tx * 4 + j - 4));
            if (gn >= N) continue;
            const size_t idx = (size_t)gm * ldc + gn;
            if constexpr (BETA == 1) {
                C[idx] += acc[i][j];
            } else if constexpr (std::is_same<CT, bf16>::value) {
                C[idx] = __float2bfloat16(acc[i][j]);
            } else {
                C[idx] = acc[i][j];
            }
        }
    }
}

// ---------------------------------------------------------------------------
// h0 = tanh(enc_hidden @ bridge_hW.T + hb); c0 = tanh(enc_cell @ bridge_cW.T + cb)
// grid = NB blocks, 256 threads
// ---------------------------------------------------------------------------
__global__ __launch_bounds__(256) void bridge_kernel(const float* __restrict__ eh,
                                                     const float* __restrict__ ec,
                                                     const float* __restrict__ hW,
                                                     const float* __restrict__ hb,
                                                     const float* __restrict__ cW,
                                                     const float* __restrict__ cb,
                                                     float* __restrict__ h0,
                                                     float* __restrict__ c0) {
    const int b = blockIdx.x;
    __shared__ float sh[1024];
    __shared__ float sc[1024];
    for (int i = threadIdx.x; i < 1024; i += 256) {
        sh[i] = eh[b * 1024 + i];
        sc[i] = ec[b * 1024 + i];
    }
    __syncthreads();
    for (int j = threadIdx.x; j < NH; j += 256) {
        const float* wh = hW + (size_t)j * 1024;
        const float* wc = cW + (size_t)j * 1024;
        float ah = 0.f, ac = 0.f;
        for (int k = 0; k < 1024; k += 4) {
            const float4 vh = *reinterpret_cast<const float4*>(wh + k);
            const float4 vc = *reinterpret_cast<const float4*>(wc + k);
            ah = fmaf(vh.x, sh[k], ah); ah = fmaf(vh.y, sh[k + 1], ah);
            ah = fmaf(vh.z, sh[k + 2], ah); ah = fmaf(vh.w, sh[k + 3], ah);
            ac = fmaf(vc.x, sc[k], ac); ac = fmaf(vc.y, sc[k + 1], ac);
            ac = fmaf(vc.z, sc[k + 2], ac); ac = fmaf(vc.w, sc[k + 3], ac);
        }
        h0[b * NH + j] = tanhf(ah + hb[j]);
        c0[b * NH + j] = tanhf(ac + cb[j]);
    }
}

// qp = h0 @ query_W.T   (per-batch matvec)
__global__ __launch_bounds__(256) void qp_kernel(const float* __restrict__ h0,
                                                 const float* __restrict__ qW,
                                                 float* __restrict__ qp) {
    const int b = blockIdx.x;
    __shared__ float sh[NH];
    for (int i = threadIdx.x; i < NH; i += 256) sh[i] = h0[b * NH + i];
    __syncthreads();
    for (int j = threadIdx.x; j < NH; j += 256) {
        const float* w = qW + (size_t)j * NH;
        float a = 0.f;
        for (int k = 0; k < NH; k += 4) {
            const float4 v = *reinterpret_cast<const float4*>(w + k);
            a = fmaf(v.x, sh[k], a); a = fmaf(v.y, sh[k + 1], a);
            a = fmaf(v.z, sh[k + 2], a); a = fmaf(v.w, sh[k + 3], a);
        }
        qp[b * NH + j] = a;
    }
}

// scores[b,s] = sum_h eW[h]*tanh(pk[b,s,h] + qp[b,h]) ; mask
// one wave per (b,s); 4 waves per block
__global__ __launch_bounds__(256) void scores_kernel(const bf16* __restrict__ pk,
                                                     const float* __restrict__ qp,
                                                     const float* __restrict__ eW,
                                                     const int* __restrict__ spos,
                                                     float* __restrict__ scores) {
    const int idx = blockIdx.x * 4 + (threadIdx.x >> 6);  // b*NS + s
    const int lane = threadIdx.x & 63;
    const int b = idx >> 8;  // NS == 256
    const unsigned short* pr =
        reinterpret_cast<const unsigned short*>(pk) + (size_t)idx * NH + lane * 8;
    const float* qr = qp + b * NH + lane * 8;
    const float* er = eW + lane * 8;
    float acc = 0.f;
#pragma unroll
    for (int i = 0; i < 8; ++i) {
        const float e = tanhf(bfu2f(pr[i]) + qr[i]);
        acc = fmaf(e, er[i], acc);
    }
#pragma unroll
    for (int o = 32; o > 0; o >>= 1) acc += __shfl_xor(acc, o);
    if (lane == 0) scores[idx] = (spos[idx] != 0) ? acc : -1000000000.0f;
}

// softmax over s (per b) + context[b,d] = sum_s alpha[s]*enc[b,s,d]
__global__ __launch_bounds__(256) void softmax_ctx_kernel(const float* __restrict__ scores,
                                                          const float* __restrict__ enc,
                                                          float* __restrict__ ctx) {
    const int b = blockIdx.x;
    const int tid = threadIdx.x;
    __shared__ float sal[NS];
    __shared__ float red[8];
    const float v = scores[b * NS + tid];
    float m = v;
#pragma unroll
    for (int o = 32; o > 0; o >>= 1) m = fmaxf(m, __shfl_xor(m, o));
    if ((tid & 63) == 0) red[tid >> 6] = m;
    __syncthreads();
    const float bm = fmaxf(fmaxf(red[0], red[1]), fmaxf(red[2], red[3]));
    const float e = expf(v - bm);
    float s = e;
#pragma unroll
    for (int o = 32; o > 0; o >>= 1) s += __shfl_xor(s, o);
    __syncthreads();
    if ((tid & 63) == 0) red[4 + (tid >> 6)] = s;
    __syncthreads();
    const float bs = red[4] + red[5] + red[6] + red[7];
    sal[tid] = e / bs;
    __syncthreads();
    float a0 = 0.f, a1 = 0.f, a2 = 0.f, a3 = 0.f;
    const float* eb = enc + (size_t)b * NS * 1024;
    for (int sI = 0; sI < NS; ++sI) {
        const float al = sal[sI];
        const float* er = eb + sI * 1024;
        a0 = fmaf(al, er[tid], a0);
        a1 = fmaf(al, er[256 + tid], a1);
        a2 = fmaf(al, er[512 + tid], a2);
        a3 = fmaf(al, er[768 + tid], a3);
    }
    ctx[b * 1024 + tid] = a0;
    ctx[b * 1024 + 256 + tid] = a1;
    ctx[b * 1024 + 512 + tid] = a2;
    ctx[b * 1024 + 768 + tid] = a3;
}

// Per-token: gather vocab tables, add per-batch bases, LSTM cell, write h (bf16)
// and the (tblO + obase) part of the output.
__global__ __launch_bounds__(256) void lstm_kernel(const int* __restrict__ tgt,
                                                   const bf16* __restrict__ tblG,
                                                   const bf16* __restrict__ tblO,
                                                   const float* __restrict__ gbase,
                                                   const float* __restrict__ obase,
                                                   const float* __restrict__ c0,
                                                   const float* __restrict__ bih,
                                                   const float* __restrict__ bhh,
                                                   bf16* __restrict__ hbuf,
                                                   float* __restrict__ out) {
    const int token = blockIdx.x;  // b*NT + t
    const int b = token >> 8;      // NT == 256
    const int v = tgt[token];
    const unsigned short* tg = reinterpret_cast<const unsigned short*>(tblG) + (size_t)v * 2048;
    const unsigned short* to = reinterpret_cast<const unsigned short*>(tblO) + (size_t)v * NH;
    const float* gb = gbase + (size_t)b * 2048;
    const float* ob = obase + (size_t)b * NH;
    const float* cb = c0 + (size_t)b * NH;
    for (int j = threadIdx.x; j < NH; j += 256) {
        const float i_ = bfu2f(tg[j])        + gb[j]        + bih[j]        + bhh[j];
        const float f_ = bfu2f(tg[512 + j])  + gb[512 + j]  + bih[512 + j]  + bhh[512 + j];
        const float g_ = bfu2f(tg[1024 + j]) + gb[1024 + j] + bih[1024 + j] + bhh[1024 + j];
        const float o_ = bfu2f(tg[1536 + j]) + gb[1536 + j] + bih[1536 + j] + bhh[1536 + j];
        const float c = sigmf(f_) * cb[j] + sigmf(i_) * tanhf(g_);
        const float h = sigmf(o_) * tanhf(c);
        hbuf[(size_t)token * NH + j] = __float2bfloat16(h);
        out[(size_t)token * NH + j] = bfu2f(to[j]) + ob[j];
    }
}

// ---------------------------------------------------------------------------
extern "C" void kernel_launch(void* const* d_in, const int* in_sizes, int n_in,
                              void* d_out, int out_size, void* d_ws, size_t ws_size,
                              hipStream_t stream) {
    const int* tgt = (const int*)d_in[0];
    const float* enc = (const float*)d_in[1];
    const float* ehid = (const float*)d_in[2];
    const float* ecell = (const float*)d_in[3];
    const int* spos = (const int*)d_in[4];
    const float* emb = (const float*)d_in[5];
    const float* keyW = (const float*)d_in[6];
    const float* qW = (const float*)d_in[7];
    const float* eW = (const float*)d_in[8];
    const float* Wih = (const float*)d_in[9];
    const float* Whh = (const float*)d_in[10];
    const float* bih = (const float*)d_in[11];
    const float* bhh = (const float*)d_in[12];
    const float* bhW = (const float*)d_in[13];
    const float* bhb = (const float*)d_in[14];
    const float* bcW = (const float*)d_in[15];
    const float* bcb = (const float*)d_in[16];
    const float* preW = (const float*)d_in[17];
    float* out = (float*)d_out;

    char* ws = (char*)d_ws;
    size_t off = 0;
    auto alloc = [&](size_t bytes) {
        void* p = ws + off;
        off += bytes;
        return p;
    };
    float* h0 = (float*)alloc((size_t)NB * NH * 4);
    float* c0 = (float*)alloc((size_t)NB * NH * 4);
    float* qp = (float*)alloc((size_t)NB * NH * 4);
    float* scores = (float*)alloc((size_t)NB * NS * 4);
    float* ctx = (float*)alloc((size_t)NB * 1024 * 4);
    float* gbase = (float*)alloc((size_t)NB * 2048 * 4);
    float* obase = (float*)alloc((size_t)NB * NH * 4);
    bf16* pk = (bf16*)alloc((size_t)NB * NS * NH * 2);
    bf16* tblG = (bf16*)alloc((size_t)NV * 2048 * 2);
    bf16* tblO = (bf16*)alloc((size_t)NV * NH * 2);
    bf16* hbuf = (bf16*)alloc((size_t)NB * NT * NH * 2);

    // 1. bridge: h0, c0
    bridge_kernel<<<NB, 256, 0, stream>>>(ehid, ecell, bhW, bhb, bcW, bcb, h0, c0);
    // 2. qp = h0 @ query_W.T
    qp_kernel<<<NB, 256, 0, stream>>>(h0, qW, qp);
    // 3. pk = enc @ key_W.T   (M=32768, N=512, K=1024) -> bf16
    gemm_nt<float, bf16, 0><<<dim3(512 / 128, 32768 / 128), 256, 0, stream>>>(
        enc, 1024, keyW, 1024, pk, NH, NB * NS, NH, 1024);
    // 4. scores
    scores_kernel<<<(NB * NS) / 4, 256, 0, stream>>>(pk, qp, eW, spos, scores);
    // 5. softmax + context
    softmax_ctx_kernel<<<NB, 256, 0, stream>>>(scores, enc, ctx);
    // 6. gbase = ctx @ W_ih[:,256:1280].T  then += h0 @ W_hh.T
    gemm_nt<float, float, 0><<<dim3(2048 / 128, 1), 256, 0, stream>>>(
        ctx, 1024, Wih + 256, 1280, gbase, 2048, NB, 2048, 1024);
    gemm_nt<float, float, 1><<<dim3(2048 / 128, 1), 256, 0, stream>>>(
        h0, NH, Whh, NH, gbase, 2048, NB, 2048, NH);
    // 7. obase = ctx @ pre_W[:,768:1792].T
    gemm_nt<float, float, 0><<<dim3(512 / 128, 1), 256, 0, stream>>>(
        ctx, 1024, preW + 768, 1792, obase, NH, NB, NH, 1024);
    // 8. vocab tables: tblG = emb @ W_ih[:,0:256].T ; tblO = emb @ pre_W[:,0:256].T
    gemm_nt<float, bf16, 0><<<dim3(2048 / 128, (NV + 127) / 128), 256, 0, stream>>>(
        emb, NE, Wih, 1280, tblG, 2048, NV, 2048, NE);
    gemm_nt<float, bf16, 0><<<dim3(512 / 128, (NV + 127) / 128), 256, 0, stream>>>(
        emb, NE, preW, 1792, tblO, NH, NV, NH, NE);
    // 9. LSTM cell per token -> hbuf (bf16), out = tblO-gather + obase
    lstm_kernel<<<NB * NT, 256, 0, stream>>>(tgt, tblG, tblO, gbase, obase, c0, bih, bhh,
                                             hbuf, out);
    // 10. out += h @ pre_W[:,256:768].T   (M=32768, N=512, K=512)
    gemm_nt<bf16, float, 1><<<dim3(512 / 128, 32768 / 128), 256, 0, stream>>>(
        hbuf, NH, preW + 256, 1792, out, NH, NB * NT, NH, NH);
}

// Round 2
// 733.034 us; speedup vs baseline: 2.4099x; 2.4099x over previous
//
#include <hip/hip_runtime.h>
#include <hip/hip_bf16.h>

// Problem dims
#define NB 128
#define NT 256
#define NS 256
#define NH 512
#define NE 256
#define NV 10000

using bf16 = __hip_bfloat16;
typedef __bf16 bf16x8 __attribute__((ext_vector_type(8)));
typedef float f32x4 __attribute__((ext_vector_type(4)));
typedef const void __attribute__((address_space(1))) gv_t;
typedef void __attribute__((address_space(3))) lv_t;

__device__ __forceinline__ float bfu2f(unsigned short u) {
    return __uint_as_float(((unsigned int)u) << 16);
}
__device__ __forceinline__ unsigned short f2bf(float f) {
    unsigned int u = __float_as_uint(f);
    return (unsigned short)((u + 0x7FFF + ((u >> 16) & 1)) >> 16);
}
__device__ __forceinline__ float sigmf(float x) { return 1.f / (1.f + expf(-x)); }

// ---------------------------------------------------------------------------
// fp32 -> bf16 conversion of all GEMM operands in one kernel (vec4 units)
// ---------------------------------------------------------------------------
#define CV0 8388608   // enc   128*256*1024 /4
#define CV1 640000    // emb   10000*256    /4
#define CV2 131072    // keyW  512*1024     /4
#define CV3 655360    // Wih   2048*1280    /4
#define CV4 262144    // Whh   2048*512     /4
#define CV5 229376    // preW  512*1792     /4
#define CVT (CV0 + CV1 + CV2 + CV3 + CV4 + CV5)

__global__ __launch_bounds__(256) void cvt_kernel(
    const float* __restrict__ enc, bf16* __restrict__ encB,
    const float* __restrict__ emb, bf16* __restrict__ embB,
    const float* __restrict__ keyW, bf16* __restrict__ keyWB,
    const float* __restrict__ Wih, bf16* __restrict__ WihB,
    const float* __restrict__ Whh, bf16* __restrict__ WhhB,
    const float* __restrict__ preW, bf16* __restrict__ preWB) {
    for (int i = blockIdx.x * 256 + threadIdx.x; i < CVT; i += gridDim.x * 256) {
        const float* s;
        unsigned short* d;
        int j = i;
        if (j < CV0) { s = enc; d = (unsigned short*)encB; }
        else { j -= CV0;
            if (j < CV1) { s = emb; d = (unsigned short*)embB; }
            else { j -= CV1;
                if (j < CV2) { s = keyW; d = (unsigned short*)keyWB; }
                else { j -= CV2;
                    if (j < CV3) { s = Wih; d = (unsigned short*)WihB; }
                    else { j -= CV3;
                        if (j < CV4) { s = Whh; d = (unsigned short*)WhhB; }
                        else { j -= CV4; s = preW; d = (unsigned short*)preWB; }
                    }
                }
            }
        }
        const float4 v = *reinterpret_cast<const float4*>(s + (size_t)j * 4);
        ushort4 o;
        o.x = f2bf(v.x); o.y = f2bf(v.y); o.z = f2bf(v.z); o.w = f2bf(v.w);
        *reinterpret_cast<ushort4*>(d + (size_t)j * 4) = o;
    }
}

// ---------------------------------------------------------------------------
// MFMA GEMM: C[M,N] = A[M,K] @ Bw[N,K]^T   (bf16 A,B; fp32 accum)
// 128x128 tile, BK=32, 256 threads (4 waves, 2x2), 16x16x32 bf16 MFMA.
// EPI 0: plain store (CT float or bf16; BETA 0/1)
// EPI 1: out = acc + tblO[tgt[gm]][gn] + obase[b][gn]   (final projection)
// EPI 2: scores[gm] atomicAdd( sum_gn eW[gn]*tanh(acc + qp[b][gn]) )
// ---------------------------------------------------------------------------
template <typename CT, int BETA, int EPI>
__global__ __launch_bounds__(256) void gemm_mfma(
    const bf16* __restrict__ A, int lda, const bf16* __restrict__ Bw, int ldb,
    CT* __restrict__ C, int ldc, int M, int N, int K,
    const int* __restrict__ e_tgt, const bf16* __restrict__ e_tbl,
    const float* __restrict__ e_v0, const float* __restrict__ e_v1) {
    __shared__ __bf16 As[128 * 32];
    __shared__ __bf16 Bs[128 * 32];
    const int t = threadIdx.x;
    const int lane = t & 63;
    const int w = t >> 6;
    const int wr = w >> 1, wc = w & 1;
    const int fr = lane & 15;
    const int fk = (lane >> 4) * 8;
    const int m0 = blockIdx.y * 128;
    const int n0 = blockIdx.x * 128;
    const int sr = t >> 2;
    const int sc = (t & 3) * 8;

    f32x4 acc[4][4];
#pragma unroll
    for (int i = 0; i < 4; ++i)
#pragma unroll
        for (int j = 0; j < 4; ++j) acc[i][j] = {0.f, 0.f, 0.f, 0.f};

    for (int k0 = 0; k0 < K; k0 += 32) {
#pragma unroll
        for (int h = 0; h < 2; ++h) {
            int gm = m0 + sr + h * 64;
            if (gm > M - 1) gm = M - 1;  // clamp (dup row; outputs bounds-checked)
            const bf16* gpA = A + (size_t)gm * lda + k0 + sc;
            __builtin_amdgcn_global_load_lds((gv_t*)gpA, (lv_t*)&As[(t + h * 256) * 8], 16, 0, 0);
            const bf16* gpB = Bw + (size_t)(n0 + sr + h * 64) * ldb + k0 + sc;
            __builtin_amdgcn_global_load_lds((gv_t*)gpB, (lv_t*)&Bs[(t + h * 256) * 8], 16, 0, 0);
        }
        __syncthreads();
        bf16x8 af[4], bfr[4];
#pragma unroll
        for (int i = 0; i < 4; ++i)
            af[i] = *reinterpret_cast<const bf16x8*>(&As[(wr * 64 + i * 16 + fr) * 32 + fk]);
#pragma unroll
        for (int j = 0; j < 4; ++j)
            bfr[j] = *reinterpret_cast<const bf16x8*>(&Bs[(wc * 64 + j * 16 + fr) * 32 + fk]);
#pragma unroll
        for (int i = 0; i < 4; ++i)
#pragma unroll
            for (int j = 0; j < 4; ++j)
                acc[i][j] = __builtin_amdgcn_mfma_f32_16x16x32_bf16(af[i], bfr[j], acc[i][j], 0, 0, 0);
        __syncthreads();
    }

    if constexpr (EPI == 2) {
        // scores fusion: per output row, sum eW[gn]*tanh(acc + qp[b][gn])
#pragma unroll
        for (int i = 0; i < 4; ++i) {
#pragma unroll
            for (int r = 0; r < 4; ++r) {
                const int gm = m0 + wr * 64 + i * 16 + (lane >> 4) * 4 + r;
                const int bb = gm >> 8;  // NS == 256
                float s = 0.f;
#pragma unroll
                for (int j = 0; j < 4; ++j) {
                    const int gn = n0 + wc * 64 + j * 16 + fr;
                    const float tv = tanhf(acc[i][j][r] + e_v0[bb * NH + gn]);
                    s = fmaf(tv, e_v1[gn], s);
                }
                s += __shfl_xor(s, 1);
                s += __shfl_xor(s, 2);
                s += __shfl_xor(s, 4);
                s += __shfl_xor(s, 8);
                if (fr == 0) atomicAdd((float*)&C[gm], s);
            }
        }
        return;
    }

#pragma unroll
    for (int i = 0; i < 4; ++i) {
#pragma unroll
        for (int r = 0; r < 4; ++r) {
            const int gm = m0 + wr * 64 + i * 16 + (lane >> 4) * 4 + r;
            if (gm >= M) continue;
            int vrow = 0;
            if constexpr (EPI == 1) vrow = e_tgt[gm];
#pragma unroll
            for (int j = 0; j < 4; ++j) {
                const int gn = n0 + wc * 64 + j * 16 + fr;
                const size_t idx = (size_t)gm * ldc + gn;
                const float v = acc[i][j][r];
                if constexpr (EPI == 1) {
                    ((float*)C)[idx] =
                        v + bfu2f(((const unsigned short*)e_tbl)[(size_t)vrow * NH + gn]) +
                        e_v0[(gm >> 8) * NH + gn];
                } else if constexpr (BETA == 1) {
                    ((float*)C)[idx] += v;
                } else if constexpr (sizeof(CT) == 2) {
                    ((unsigned short*)C)[idx] = f2bf(v);
                } else {
                    ((float*)C)[idx] = v;
                }
            }
        }
    }
}

// ---------------------------------------------------------------------------
// h0 = tanh(eh @ bhW.T + hb); c0 = tanh(ec @ bcW.T + cb); also h0 in bf16
// ---------------------------------------------------------------------------
__global__ __launch_bounds__(256) void bridge_kernel(
    const float* __restrict__ eh, const float* __restrict__ ec,
    const float* __restrict__ hW, const float* __restrict__ hb,
    const float* __restrict__ cW, const float* __restrict__ cb,
    float* __restrict__ h0, float* __restrict__ c0, bf16* __restrict__ h0b) {
    const int b = blockIdx.x;
    __shared__ float sh[1024];
    __shared__ float sc_[1024];
    for (int i = threadIdx.x; i < 1024; i += 256) {
        sh[i] = eh[b * 1024 + i];
        sc_[i] = ec[b * 1024 + i];
    }
    __syncthreads();
    for (int j = threadIdx.x; j < NH; j += 256) {
        const float* wh = hW + (size_t)j * 1024;
        const float* wc = cW + (size_t)j * 1024;
        float ah = 0.f, ac = 0.f;
        for (int k = 0; k < 1024; k += 4) {
            const float4 vh = *reinterpret_cast<const float4*>(wh + k);
            const float4 vc = *reinterpret_cast<const float4*>(wc + k);
            ah = fmaf(vh.x, sh[k], ah); ah = fmaf(vh.y, sh[k + 1], ah);
            ah = fmaf(vh.z, sh[k + 2], ah); ah = fmaf(vh.w, sh[k + 3], ah);
            ac = fmaf(vc.x, sc_[k], ac); ac = fmaf(vc.y, sc_[k + 1], ac);
            ac = fmaf(vc.z, sc_[k + 2], ac); ac = fmaf(vc.w, sc_[k + 3], ac);
        }
        const float th = tanhf(ah + hb[j]);
        h0[b * NH + j] = th;
        ((unsigned short*)h0b)[b * NH + j] = f2bf(th);
        c0[b * NH + j] = tanhf(ac + cb[j]);
    }
}

// qp = h0 @ query_W.T  (per-batch matvec, fp32)
__global__ __launch_bounds__(256) void qp_kernel(const float* __restrict__ h0,
                                                 const float* __restrict__ qW,
                                                 float* __restrict__ qp) {
    const int b = blockIdx.x;
    __shared__ float sh[NH];
    for (int i = threadIdx.x; i < NH; i += 256) sh[i] = h0[b * NH + i];
    __syncthreads();
    for (int j = threadIdx.x; j < NH; j += 256) {
        const float* wp = qW + (size_t)j * NH;
        float a = 0.f;
        for (int k = 0; k < NH; k += 4) {
            const float4 v = *reinterpret_cast<const float4*>(wp + k);
            a = fmaf(v.x, sh[k], a); a = fmaf(v.y, sh[k + 1], a);
            a = fmaf(v.z, sh[k + 2], a); a = fmaf(v.w, sh[k + 3], a);
        }
        qp[b * NH + j] = a;
    }
}

// softmax over scores -> alphas (one block per b)
__global__ __launch_bounds__(256) void softmax_kernel(const float* __restrict__ scores,
                                                      const int* __restrict__ spos,
                                                      float* __restrict__ alphas) {
    const int b = blockIdx.x;
    const int tid = threadIdx.x;
    __shared__ float red[8];
    float v = scores[b * NS + tid];
    if (spos[b * NS + tid] == 0) v = -1000000000.0f;
    float m = v;
#pragma unroll
    for (int o = 32; o > 0; o >>= 1) m = fmaxf(m, __shfl_xor(m, o));
    if ((tid & 63) == 0) red[tid >> 6] = m;
    __syncthreads();
    const float bm = fmaxf(fmaxf(red[0], red[1]), fmaxf(red[2], red[3]));
    const float e = expf(v - bm);
    float s = e;
#pragma unroll
    for (int o = 32; o > 0; o >>= 1) s += __shfl_xor(s, o);
    if ((tid & 63) == 0) red[4 + (tid >> 6)] = s;
    __syncthreads();
    const float bs = red[4] + red[5] + red[6] + red[7];
    alphas[b * NS + tid] = e / bs;
}

// partial context: block (b, chunk of 64 s) -> partial[b*4+c][1024]
__global__ __launch_bounds__(256) void ctx_partial_kernel(const bf16* __restrict__ encB,
                                                          const float* __restrict__ alphas,
                                                          float* __restrict__ partial) {
    const int blk = blockIdx.x;
    const int b = blk >> 2, c = blk & 3;
    const int tid = threadIdx.x;
    __shared__ float sal[64];
    if (tid < 64) sal[tid] = alphas[b * NS + c * 64 + tid];
    __syncthreads();
    const int d0 = tid * 4;
    float a0 = 0.f, a1 = 0.f, a2 = 0.f, a3 = 0.f;
    const unsigned short* eb =
        (const unsigned short*)encB + ((size_t)(b * NS + c * 64)) * 1024 + d0;
    for (int s = 0; s < 64; ++s) {
        const ushort4 v = *reinterpret_cast<const ushort4*>(eb + (size_t)s * 1024);
        const float al = sal[s];
        a0 = fmaf(al, bfu2f(v.x), a0);
        a1 = fmaf(al, bfu2f(v.y), a1);
        a2 = fmaf(al, bfu2f(v.z), a2);
        a3 = fmaf(al, bfu2f(v.w), a3);
    }
    float4 o = {a0, a1, a2, a3};
    *reinterpret_cast<float4*>(&partial[(size_t)blk * 1024 + d0]) = o;
}

// combine 4 partials -> ctxB (bf16)
__global__ __launch_bounds__(256) void ctx_combine_kernel(const float* __restrict__ partial,
                                                          bf16* __restrict__ ctxB) {
    const int idx = blockIdx.x * 256 + threadIdx.x;  // 128*1024
    const int b = idx >> 10, d = idx & 1023;
    const float s = partial[(size_t)(b * 4 + 0) * 1024 + d] +
                    partial[(size_t)(b * 4 + 1) * 1024 + d] +
                    partial[(size_t)(b * 4 + 2) * 1024 + d] +
                    partial[(size_t)(b * 4 + 3) * 1024 + d];
    ((unsigned short*)ctxB)[idx] = f2bf(s);
}

// LSTM cell per token: gather tblG, add gbase+biases, write h (bf16)
__global__ __launch_bounds__(256) void lstm_kernel(const int* __restrict__ tgt,
                                                   const bf16* __restrict__ tblG,
                                                   const float* __restrict__ gbase,
                                                   const float* __restrict__ c0,
                                                   const float* __restrict__ bih,
                                                   const float* __restrict__ bhh,
                                                   bf16* __restrict__ hbuf) {
    const int token = blockIdx.x;  // b*NT + t
    const int b = token >> 8;      // NT == 256
    const int v = tgt[token];
    const unsigned short* tg = (const unsigned short*)tblG + (size_t)v * 2048;
    const float* gb = gbase + (size_t)b * 2048;
    const float* cb = c0 + (size_t)b * NH;
    for (int j = threadIdx.x; j < NH; j += 256) {
        const float i_ = bfu2f(tg[j]) + gb[j] + bih[j] + bhh[j];
        const float f_ = bfu2f(tg[512 + j]) + gb[512 + j] + bih[512 + j] + bhh[512 + j];
        const float g_ = bfu2f(tg[1024 + j]) + gb[1024 + j] + bih[1024 + j] + bhh[1024 + j];
        const float o_ = bfu2f(tg[1536 + j]) + gb[1536 + j] + bih[1536 + j] + bhh[1536 + j];
        const float c = sigmf(f_) * cb[j] + sigmf(i_) * tanhf(g_);
        const float h = sigmf(o_) * tanhf(c);
        ((unsigned short*)hbuf)[(size_t)token * NH + j] = f2bf(h);
    }
}

// ---------------------------------------------------------------------------
extern "C" void kernel_launch(void* const* d_in, const int* in_sizes, int n_in,
                              void* d_out, int out_size, void* d_ws, size_t ws_size,
                              hipStream_t stream) {
    const int* tgt = (const int*)d_in[0];
    const float* enc = (const float*)d_in[1];
    const float* ehid = (const float*)d_in[2];
    const float* ecell = (const float*)d_in[3];
    const int* spos = (const int*)d_in[4];
    const float* emb = (const float*)d_in[5];
    const float* keyW = (const float*)d_in[6];
    const float* qW = (const float*)d_in[7];
    const float* eW = (const float*)d_in[8];
    const float* Wih = (const float*)d_in[9];
    const float* Whh = (const float*)d_in[10];
    const float* bih = (const float*)d_in[11];
    const float* bhh = (const float*)d_in[12];
    const float* bhW = (const float*)d_in[13];
    const float* bhb = (const float*)d_in[14];
    const float* bcW = (const float*)d_in[15];
    const float* bcb = (const float*)d_in[16];
    const float* preW = (const float*)d_in[17];
    float* out = (float*)d_out;

    char* ws = (char*)d_ws;
    size_t off = 0;
    auto alloc = [&](size_t bytes) {
        void* p = ws + off;
        off += (bytes + 255) & ~(size_t)255;
        return p;
    };
    bf16* encB = (bf16*)alloc((size_t)NB * NS * 1024 * 2);
    bf16* embB = (bf16*)alloc((size_t)NV * NE * 2);
    bf16* keyWB = (bf16*)alloc((size_t)NH * 1024 * 2);
    bf16* WihB = (bf16*)alloc((size_t)2048 * 1280 * 2);
    bf16* WhhB = (bf16*)alloc((size_t)2048 * 512 * 2);
    bf16* preWB = (bf16*)alloc((size_t)512 * 1792 * 2);
    float* h0 = (float*)alloc((size_t)NB * NH * 4);
    float* c0 = (float*)alloc((size_t)NB * NH * 4);
    bf16* h0b = (bf16*)alloc((size_t)NB * NH * 2);
    float* qp = (float*)alloc((size_t)NB * NH * 4);
    float* scores = (float*)alloc((size_t)NB * NS * 4);
    float* alphas = (float*)alloc((size_t)NB * NS * 4);
    float* partial = (float*)alloc((size_t)NB * 4 * 1024 * 4);
    bf16* ctxB = (bf16*)alloc((size_t)NB * 1024 * 2);
    float* gbase = (float*)alloc((size_t)NB * 2048 * 4);
    float* obase = (float*)alloc((size_t)NB * NH * 4);
    bf16* tblG = (bf16*)alloc((size_t)NV * 2048 * 2);
    bf16* tblO = (bf16*)alloc((size_t)NV * NH * 2);
    bf16* hbuf = (bf16*)alloc((size_t)NB * NT * NH * 2);

    // 1. bf16 conversions
    cvt_kernel<<<2048, 256, 0, stream>>>(enc, encB, emb, embB, keyW, keyWB, Wih, WihB,
                                         Whh, WhhB, preW, preWB);
    // 2. bridge
    bridge_kernel<<<NB, 256, 0, stream>>>(ehid, ecell, bhW, bhb, bcW, bcb, h0, c0, h0b);
    // 3. qp
    qp_kernel<<<NB, 256, 0, stream>>>(h0, qW, qp);
    // 4. scores = 0
    hipMemsetAsync(scores, 0, (size_t)NB * NS * 4, stream);
    // 5. pk GEMM fused with scores reduction (EPI=2)
    gemm_mfma<float, 0, 2><<<dim3(4, 256), 256, 0, stream>>>(
        encB, 1024, keyWB, 1024, scores, 0, NB * NS, NH, 1024, nullptr, nullptr, qp, eW);
    // 6. softmax -> alphas
    softmax_kernel<<<NB, 256, 0, stream>>>(scores, spos, alphas);
    // 7-8. context
    ctx_partial_kernel<<<NB * 4, 256, 0, stream>>>(encB, alphas, partial);
    ctx_combine_kernel<<<512, 256, 0, stream>>>(partial, ctxB);
    // 9-10. gbase = ctx @ Wih[:,256:1280].T + h0 @ Whh.T
    gemm_mfma<float, 0, 0><<<dim3(16, 1), 256, 0, stream>>>(
        ctxB, 1024, WihB + 256, 1280, gbase, 2048, NB, 2048, 1024, nullptr, nullptr, nullptr, nullptr);
    gemm_mfma<float, 1, 0><<<dim3(16, 1), 256, 0, stream>>>(
        h0b, 512, WhhB, 512, gbase, 2048, NB, 2048, 512, nullptr, nullptr, nullptr, nullptr);
    // 11. obase = ctx @ pre_W[:,768:1792].T
    gemm_mfma<float, 0, 0><<<dim3(4, 1), 256, 0, stream>>>(
        ctxB, 1024, preWB + 768, 1792, obase, NH, NB, NH, 1024, nullptr, nullptr, nullptr, nullptr);
    // 12-13. vocab tables
    gemm_mfma<bf16, 0, 0><<<dim3(16, 79), 256, 0, stream>>>(
        embB, 256, WihB, 1280, tblG, 2048, NV, 2048, 256, nullptr, nullptr, nullptr, nullptr);
    gemm_mfma<bf16, 0, 0><<<dim3(4, 79), 256, 0, stream>>>(
        embB, 256, preWB, 1792, tblO, NH, NV, NH, 256, nullptr, nullptr, nullptr, nullptr);
    // 14. LSTM cell -> hbuf
    lstm_kernel<<<NB * NT, 256, 0, stream>>>(tgt, tblG, gbase, c0, bih, bhh, hbuf);
    // 15. out = hbuf @ pre_W[:,256:768].T + gather(tblO) + obase  (EPI=1)
    gemm_mfma<float, 0, 1><<<dim3(4, 256), 256, 0, stream>>>(
        hbuf, 512, preWB + 256, 1792, out, NH, NB * NT, NH, 512, tgt, tblO, obase, nullptr);
}

// Round 6
// 674.234 us; speedup vs baseline: 2.6201x; 1.0872x over previous
//
#include <hip/hip_runtime.h>
#include <hip/hip_bf16.h>

// Problem dims
#define NB 128
#define NT 256
#define NS 256
#define NH 512
#define NE 256
#define NV 10000

using bf16 = __hip_bfloat16;
typedef __bf16 bf16x8 __attribute__((ext_vector_type(8)));
typedef float f32x4 __attribute__((ext_vector_type(4)));
typedef const void __attribute__((address_space(1))) gv_t;
typedef void __attribute__((address_space(3))) lv_t;

__device__ __forceinline__ float bfu2f(unsigned short u) {
    return __uint_as_float(((unsigned int)u) << 16);
}
__device__ __forceinline__ unsigned short f2bf(float f) {
    unsigned int u = __float_as_uint(f);
    return (unsigned short)((u + 0x7FFF + ((u >> 16) & 1)) >> 16);
}
__device__ __forceinline__ float sigmf(float x) { return 1.f / (1.f + expf(-x)); }

// ---------------------------------------------------------------------------
// fp32 -> bf16 conversion of all GEMM operands in one kernel (vec4 units)
// ---------------------------------------------------------------------------
#define CV0 8388608   // enc   128*256*1024 /4
#define CV1 640000    // emb   10000*256    /4
#define CV2 131072    // keyW  512*1024     /4
#define CV3 655360    // Wih   2048*1280    /4
#define CV4 262144    // Whh   2048*512     /4
#define CV5 229376    // preW  512*1792     /4
#define CV6 32768     // ehid  128*1024     /4
#define CV7 32768     // ecell 128*1024     /4
#define CV8 131072    // bhW   512*1024     /4
#define CV9 131072    // bcW   512*1024     /4
#define CV10 65536    // qW    512*512      /4
#define CVT (CV0 + CV1 + CV2 + CV3 + CV4 + CV5 + CV6 + CV7 + CV8 + CV9 + CV10)

__global__ __launch_bounds__(256) void cvt_kernel(
    const float* __restrict__ enc, bf16* __restrict__ encB,
    const float* __restrict__ emb, bf16* __restrict__ embB,
    const float* __restrict__ keyW, bf16* __restrict__ keyWB,
    const float* __restrict__ Wih, bf16* __restrict__ WihB,
    const float* __restrict__ Whh, bf16* __restrict__ WhhB,
    const float* __restrict__ preW, bf16* __restrict__ preWB,
    const float* __restrict__ eh, bf16* __restrict__ ehB,
    const float* __restrict__ ec, bf16* __restrict__ ecB,
    const float* __restrict__ bhW, bf16* __restrict__ bhWB,
    const float* __restrict__ bcW, bf16* __restrict__ bcWB,
    const float* __restrict__ qW, bf16* __restrict__ qWB) {
    for (int i = blockIdx.x * 256 + threadIdx.x; i < CVT; i += gridDim.x * 256) {
        const float* s;
        unsigned short* d;
        int j = i;
        if (j < CV0) { s = enc; d = (unsigned short*)encB; }
        else { j -= CV0;
        if (j < CV1) { s = emb; d = (unsigned short*)embB; }
        else { j -= CV1;
        if (j < CV2) { s = keyW; d = (unsigned short*)keyWB; }
        else { j -= CV2;
        if (j < CV3) { s = Wih; d = (unsigned short*)WihB; }
        else { j -= CV3;
        if (j < CV4) { s = Whh; d = (unsigned short*)WhhB; }
        else { j -= CV4;
        if (j < CV5) { s = preW; d = (unsigned short*)preWB; }
        else { j -= CV5;
        if (j < CV6) { s = eh; d = (unsigned short*)ehB; }
        else { j -= CV6;
        if (j < CV7) { s = ec; d = (unsigned short*)ecB; }
        else { j -= CV7;
        if (j < CV8) { s = bhW; d = (unsigned short*)bhWB; }
        else { j -= CV8;
        if (j < CV9) { s = bcW; d = (unsigned short*)bcWB; }
        else { j -= CV9; s = qW; d = (unsigned short*)qWB; }
        }}}}}}}}}
        const float4 v = *reinterpret_cast<const float4*>(s + (size_t)j * 4);
        ushort4 o;
        o.x = f2bf(v.x); o.y = f2bf(v.y); o.z = f2bf(v.z); o.w = f2bf(v.w);
        *reinterpret_cast<ushort4*>(d + (size_t)j * 4) = o;
    }
}

// ---------------------------------------------------------------------------
// MFMA GEMM: C[M,N] = A[M,K] @ Bw[N,K]^T   (bf16 A,B; fp32 accum)
// 128x128 tile, BK=32, 256 threads (4 waves, 2x2), 16x16x32 bf16 MFMA.
// EPI 0: plain store (CT float or bf16; BETA 0/1)
// EPI 1: out = acc + tblO[tgt[gm]][gn] + obase[b][gn]   (final projection)
// EPI 2: scores[gm] atomicAdd( sum_gn eW[gn]*tanh(acc + qp[b][gn]) )
// EPI 3: v = tanh(acc + bias[gn]); C[gm][gn] = v (f32); optional bf16 aux store
// ---------------------------------------------------------------------------
template <typename CT, int BETA, int EPI>
__global__ __launch_bounds__(256) void gemm_mfma(
    const bf16* __restrict__ A, int lda, const bf16* __restrict__ Bw, int ldb,
    CT* __restrict__ C, int ldc, int M, int N, int K,
    const int* __restrict__ e_tgt, bf16* __restrict__ e_tbl,
    const float* __restrict__ e_v0, const float* __restrict__ e_v1) {
    __shared__ __bf16 As[128 * 32];
    __shared__ __bf16 Bs[128 * 32];
    const int t = threadIdx.x;
    const int lane = t & 63;
    const int w = t >> 6;
    const int wr = w >> 1, wc = w & 1;
    const int fr = lane & 15;
    const int fk = (lane >> 4) * 8;
    const int m0 = blockIdx.y * 128;
    const int n0 = blockIdx.x * 128;
    const int sr = t >> 2;
    const int sc = (t & 3) * 8;

    f32x4 acc[4][4];
#pragma unroll
    for (int i = 0; i < 4; ++i)
#pragma unroll
        for (int j = 0; j < 4; ++j) acc[i][j] = {0.f, 0.f, 0.f, 0.f};

    for (int k0 = 0; k0 < K; k0 += 32) {
#pragma unroll
        for (int h = 0; h < 2; ++h) {
            int gm = m0 + sr + h * 64;
            if (gm > M - 1) gm = M - 1;  // clamp (dup row; outputs bounds-checked)
            const bf16* gpA = A + (size_t)gm * lda + k0 + sc;
            __builtin_amdgcn_global_load_lds((gv_t*)gpA, (lv_t*)&As[(t + h * 256) * 8], 16, 0, 0);
            const bf16* gpB = Bw + (size_t)(n0 + sr + h * 64) * ldb + k0 + sc;
            __builtin_amdgcn_global_load_lds((gv_t*)gpB, (lv_t*)&Bs[(t + h * 256) * 8], 16, 0, 0);
        }
        __syncthreads();
        bf16x8 af[4], bfr[4];
#pragma unroll
        for (int i = 0; i < 4; ++i)
            af[i] = *reinterpret_cast<const bf16x8*>(&As[(wr * 64 + i * 16 + fr) * 32 + fk]);
#pragma unroll
        for (int j = 0; j < 4; ++j)
            bfr[j] = *reinterpret_cast<const bf16x8*>(&Bs[(wc * 64 + j * 16 + fr) * 32 + fk]);
#pragma unroll
        for (int i = 0; i < 4; ++i)
#pragma unroll
            for (int j = 0; j < 4; ++j)
                acc[i][j] = __builtin_amdgcn_mfma_f32_16x16x32_bf16(af[i], bfr[j], acc[i][j], 0, 0, 0);
        __syncthreads();
    }

    if constexpr (EPI == 2) {
        // scores fusion: per output row, sum eW[gn]*tanh(acc + qp[b][gn])
#pragma unroll
        for (int i = 0; i < 4; ++i) {
#pragma unroll
            for (int r = 0; r < 4; ++r) {
                const int gm = m0 + wr * 64 + i * 16 + (lane >> 4) * 4 + r;
                const int bb = gm >> 8;  // NS == 256
                float s = 0.f;
#pragma unroll
                for (int j = 0; j < 4; ++j) {
                    const int gn = n0 + wc * 64 + j * 16 + fr;
                    const float tv = tanhf(acc[i][j][r] + e_v0[bb * NH + gn]);
                    s = fmaf(tv, e_v1[gn], s);
                }
                s += __shfl_xor(s, 1);
                s += __shfl_xor(s, 2);
                s += __shfl_xor(s, 4);
                s += __shfl_xor(s, 8);
                if (fr == 0) atomicAdd((float*)&C[gm], s);
            }
        }
        return;
    }

#pragma unroll
    for (int i = 0; i < 4; ++i) {
#pragma unroll
        for (int r = 0; r < 4; ++r) {
            const int gm = m0 + wr * 64 + i * 16 + (lane >> 4) * 4 + r;
            if (gm >= M) continue;
            int vrow = 0;
            if constexpr (EPI == 1) vrow = e_tgt[gm];
#pragma unroll
            for (int j = 0; j < 4; ++j) {
                const int gn = n0 + wc * 64 + j * 16 + fr;
                const size_t idx = (size_t)gm * ldc + gn;
                const float v = acc[i][j][r];
                if constexpr (EPI == 1) {
                    ((float*)C)[idx] =
                        v + bfu2f(((const unsigned short*)e_tbl)[(size_t)vrow * NH + gn]) +
                        e_v0[(gm >> 8) * NH + gn];
                } else if constexpr (EPI == 3) {
                    const float tv = tanhf(v + e_v0[gn]);
                    ((float*)C)[idx] = tv;
                    if (e_tbl) ((unsigned short*)e_tbl)[idx] = f2bf(tv);
                } else if constexpr (BETA == 1) {
                    ((float*)C)[idx] += v;
                } else if constexpr (sizeof(CT) == 2) {
                    ((unsigned short*)C)[idx] = f2bf(v);
                } else {
                    ((float*)C)[idx] = v;
                }
            }
        }
    }
}

// softmax over scores -> alphas (one block per b)
__global__ __launch_bounds__(256) void softmax_kernel(const float* __restrict__ scores,
                                                      const int* __restrict__ spos,
                                                      float* __restrict__ alphas) {
    const int b = blockIdx.x;
    const int tid = threadIdx.x;
    __shared__ float red[8];
    float v = scores[b * NS + tid];
    if (spos[b * NS + tid] == 0) v = -1000000000.0f;
    float m = v;
#pragma unroll
    for (int o = 32; o > 0; o >>= 1) m = fmaxf(m, __shfl_xor(m, o));
    if ((tid & 63) == 0) red[tid >> 6] = m;
    __syncthreads();
    const float bm = fmaxf(fmaxf(red[0], red[1]), fmaxf(red[2], red[3]));
    const float e = expf(v - bm);
    float s = e;
#pragma unroll
    for (int o = 32; o > 0; o >>= 1) s += __shfl_xor(s, o);
    if ((tid & 63) == 0) red[4 + (tid >> 6)] = s;
    __syncthreads();
    const float bs = red[4] + red[5] + red[6] + red[7];
    alphas[b * NS + tid] = e / bs;
}

// partial context: block (b, chunk of 64 s) -> partial[b*4+c][1024]
__global__ __launch_bounds__(256) void ctx_partial_kernel(const bf16* __restrict__ encB,
                                                          const float* __restrict__ alphas,
                                                          float* __restrict__ partial) {
    const int blk = blockIdx.x;
    const int b = blk >> 2, c = blk & 3;
    const int tid = threadIdx.x;
    __shared__ float sal[64];
    if (tid < 64) sal[tid] = alphas[b * NS + c * 64 + tid];
    __syncthreads();
    const int d0 = tid * 4;
    float a0 = 0.f, a1 = 0.f, a2 = 0.f, a3 = 0.f;
    const unsigned short* eb =
        (const unsigned short*)encB + ((size_t)(b * NS + c * 64)) * 1024 + d0;
    for (int s = 0; s < 64; ++s) {
        const ushort4 v = *reinterpret_cast<const ushort4*>(eb + (size_t)s * 1024);
        const float al = sal[s];
        a0 = fmaf(al, bfu2f(v.x), a0);
        a1 = fmaf(al, bfu2f(v.y), a1);
        a2 = fmaf(al, bfu2f(v.z), a2);
        a3 = fmaf(al, bfu2f(v.w), a3);
    }
    float4 o = {a0, a1, a2, a3};
    *reinterpret_cast<float4*>(&partial[(size_t)blk * 1024 + d0]) = o;
}

// combine 4 partials -> ctxB (bf16)
__global__ __launch_bounds__(256) void ctx_combine_kernel(const float* __restrict__ partial,
                                                          bf16* __restrict__ ctxB) {
    const int idx = blockIdx.x * 256 + threadIdx.x;  // 128*1024
    const int b = idx >> 10, d = idx & 1023;
    const float s = partial[(size_t)(b * 4 + 0) * 1024 + d] +
                    partial[(size_t)(b * 4 + 1) * 1024 + d] +
                    partial[(size_t)(b * 4 + 2) * 1024 + d] +
                    partial[(size_t)(b * 4 + 3) * 1024 + d];
    ((unsigned short*)ctxB)[idx] = f2bf(s);
}

// LSTM cell per token: gather tblG, add gbase+biases, write h (bf16)
__global__ __launch_bounds__(256) void lstm_kernel(const int* __restrict__ tgt,
                                                   const bf16* __restrict__ tblG,
                                                   const float* __restrict__ gbase,
                                                   const float* __restrict__ c0,
                                                   const float* __restrict__ bih,
                                                   const float* __restrict__ bhh,
                                                   bf16* __restrict__ hbuf) {
    const int token = blockIdx.x;  // b*NT + t
    const int b = token >> 8;      // NT == 256
    const int v = tgt[token];
    const unsigned short* tg = (const unsigned short*)tblG + (size_t)v * 2048;
    const float* gb = gbase + (size_t)b * 2048;
    const float* cb = c0 + (size_t)b * NH;
    for (int j = threadIdx.x; j < NH; j += 256) {
        const float i_ = bfu2f(tg[j]) + gb[j] + bih[j] + bhh[j];
        const float f_ = bfu2f(tg[512 + j]) + gb[512 + j] + bih[512 + j] + bhh[512 + j];
        const float g_ = bfu2f(tg[1024 + j]) + gb[1024 + j] + bih[1024 + j] + bhh[1024 + j];
        const float o_ = bfu2f(tg[1536 + j]) + gb[1536 + j] + bih[1536 + j] + bhh[1536 + j];
        const float c = sigmf(f_) * cb[j] + sigmf(i_) * tanhf(g_);
        const float h = sigmf(o_) * tanhf(c);
        ((unsigned short*)hbuf)[(size_t)token * NH + j] = f2bf(h);
    }
}

// ---------------------------------------------------------------------------
extern "C" void kernel_launch(void* const* d_in, const int* in_sizes, int n_in,
                              void* d_out, int out_size, void* d_ws, size_t ws_size,
                              hipStream_t stream) {
    const int* tgt = (const int*)d_in[0];
    const float* enc = (const float*)d_in[1];
    const float* ehid = (const float*)d_in[2];
    const float* ecell = (const float*)d_in[3];
    const int* spos = (const int*)d_in[4];
    const float* emb = (const float*)d_in[5];
    const float* keyW = (const float*)d_in[6];
    const float* qW = (const float*)d_in[7];
    const float* eW = (const float*)d_in[8];
    const float* Wih = (const float*)d_in[9];
    const float* Whh = (const float*)d_in[10];
    const float* bih = (const float*)d_in[11];
    const float* bhh = (const float*)d_in[12];
    const float* bhW = (const float*)d_in[13];
    const float* bhb = (const float*)d_in[14];
    const float* bcW = (const float*)d_in[15];
    const float* bcb = (const float*)d_in[16];
    const float* preW = (const float*)d_in[17];
    float* out = (float*)d_out;

    char* ws = (char*)d_ws;
    size_t off = 0;
    auto alloc = [&](size_t bytes) {
        void* p = ws + off;
        off += (bytes + 255) & ~(size_t)255;
        return p;
    };
    bf16* encB = (bf16*)alloc((size_t)NB * NS * 1024 * 2);
    bf16* embB = (bf16*)alloc((size_t)NV * NE * 2);
    bf16* keyWB = (bf16*)alloc((size_t)NH * 1024 * 2);
    bf16* WihB = (bf16*)alloc((size_t)2048 * 1280 * 2);
    bf16* WhhB = (bf16*)alloc((size_t)2048 * 512 * 2);
    bf16* preWB = (bf16*)alloc((size_t)512 * 1792 * 2);
    bf16* ehB = (bf16*)alloc((size_t)NB * 1024 * 2);
    bf16* ecB = (bf16*)alloc((size_t)NB * 1024 * 2);
    bf16* bhWB = (bf16*)alloc((size_t)NH * 1024 * 2);
    bf16* bcWB = (bf16*)alloc((size_t)NH * 1024 * 2);
    bf16* qWB = (bf16*)alloc((size_t)NH * NH * 2);
    float* h0 = (float*)alloc((size_t)NB * NH * 4);
    float* c0 = (float*)alloc((size_t)NB * NH * 4);
    bf16* h0b = (bf16*)alloc((size_t)NB * NH * 2);
    float* qp = (float*)alloc((size_t)NB * NH * 4);
    float* scores = (float*)alloc((size_t)NB * NS * 4);
    float* alphas = (float*)alloc((size_t)NB * NS * 4);
    float* partial = (float*)alloc((size_t)NB * 4 * 1024 * 4);
    bf16* ctxB = (bf16*)alloc((size_t)NB * 1024 * 2);
    float* gbase = (float*)alloc((size_t)NB * 2048 * 4);
    float* obase = (float*)alloc((size_t)NB * NH * 4);
    bf16* tblG = (bf16*)alloc((size_t)NV * 2048 * 2);
    bf16* tblO = (bf16*)alloc((size_t)NV * NH * 2);
    bf16* hbuf = (bf16*)alloc((size_t)NB * NT * NH * 2);

    // 1. bf16 conversions
    cvt_kernel<<<2048, 256, 0, stream>>>(enc, encB, emb, embB, keyW, keyWB, Wih, WihB,
                                         Whh, WhhB, preW, preWB, ehid, ehB, ecell, ecB,
                                         bhW, bhWB, bcW, bcWB, qW, qWB);
    // 2. bridge via MFMA: h0 = tanh(eh @ bhW.T + bhb) -> f32 + bf16; c0 likewise (f32)
    gemm_mfma<float, 0, 3><<<dim3(4, 1), 256, 0, stream>>>(
        ehB, 1024, bhWB, 1024, h0, NH, NB, NH, 1024, nullptr, h0b, bhb, nullptr);
    gemm_mfma<float, 0, 3><<<dim3(4, 1), 256, 0, stream>>>(
        ecB, 1024, bcWB, 1024, c0, NH, NB, NH, 1024, nullptr, nullptr, bcb, nullptr);
    // 3. qp = h0 @ query_W.T via MFMA
    gemm_mfma<float, 0, 0><<<dim3(4, 1), 256, 0, stream>>>(
        h0b, NH, qWB, NH, qp, NH, NB, NH, NH, nullptr, nullptr, nullptr, nullptr);
    // 4. scores = 0
    hipMemsetAsync(scores, 0, (size_t)NB * NS * 4, stream);
    // 5. pk GEMM fused with scores reduction (EPI=2)
    gemm_mfma<float, 0, 2><<<dim3(4, 256), 256, 0, stream>>>(
        encB, 1024, keyWB, 1024, scores, 0, NB * NS, NH, 1024, nullptr, nullptr, qp, eW);
    // 6. softmax -> alphas
    softmax_kernel<<<NB, 256, 0, stream>>>(scores, spos, alphas);
    // 7-8. context
    ctx_partial_kernel<<<NB * 4, 256, 0, stream>>>(encB, alphas, partial);
    ctx_combine_kernel<<<512, 256, 0, stream>>>(partial, ctxB);
    // 9-10. gbase = ctx @ Wih[:,256:1280].T + h0 @ Whh.T
    gemm_mfma<float, 0, 0><<<dim3(16, 1), 256, 0, stream>>>(
        ctxB, 1024, WihB + 256, 1280, gbase, 2048, NB, 2048, 1024, nullptr, nullptr, nullptr, nullptr);
    gemm_mfma<float, 1, 0><<<dim3(16, 1), 256, 0, stream>>>(
        h0b, 512, WhhB, 512, gbase, 2048, NB, 2048, 512, nullptr, nullptr, nullptr, nullptr);
    // 11. obase = ctx @ pre_W[:,768:1792].T
    gemm_mfma<float, 0, 0><<<dim3(4, 1), 256, 0, stream>>>(
        ctxB, 1024, preWB + 768, 1792, obase, NH, NB, NH, 1024, nullptr, nullptr, nullptr, nullptr);
    // 12-13. vocab tables
    gemm_mfma<bf16, 0, 0><<<dim3(16, 79), 256, 0, stream>>>(
        embB, 256, WihB, 1280, tblG, 2048, NV, 2048, 256, nullptr, nullptr, nullptr, nullptr);
    gemm_mfma<bf16, 0, 0><<<dim3(4, 79), 256, 0, stream>>>(
        embB, 256, preWB, 1792, tblO, NH, NV, NH, 256, nullptr, nullptr, nullptr, nullptr);
    // 14. LSTM cell -> hbuf
    lstm_kernel<<<NB * NT, 256, 0, stream>>>(tgt, tblG, gbase, c0, bih, bhh, hbuf);
    // 15. out = hbuf @ pre_W[:,256:768].T + gather(tblO) + obase  (EPI=1)
    gemm_mfma<float, 0, 1><<<dim3(4, 256), 256, 0, stream>>>(
        hbuf, 512, preWB + 256, 1792, out, NH, NB * NT, NH, 512, tgt, tblO, obase, nullptr);
}